// Round 3
// baseline (486.612 us; speedup 1.0000x reference)
//
#include <hip/hip_runtime.h>
#include <math.h>

#define NK 512
#define DD 256
#define NB 32
#define NT 4096

typedef __attribute__((ext_vector_type(8))) _Float16 f16x8;
typedef __attribute__((ext_vector_type(4))) float f32x4;

#define MARGIN 1.5e-4f
#define DCH 16      // d per chunk
#define NCH 16      // chunks (DD/DCH)
#define ASTR 536    // tier-2 kernel LDS row stride (shorts)

__device__ __forceinline__ unsigned short f16bits(float x) {
    _Float16 h = (_Float16)x;           // v_cvt_f16_f32, RNE
    unsigned short s;
    __builtin_memcpy(&s, &h, 2);
    return s;
}

__device__ __forceinline__ void gl_lds16(const void* g, void* l) {
    __builtin_amdgcn_global_load_lds(
        (const __attribute__((address_space(1))) unsigned int*)(g),
        (__attribute__((address_space(3))) unsigned int*)(l), 16, 0, 0);
}

// ---------------------------------------------------------------------------
// Prep W: blocks 0..15 build Wpp (f16 w*4096, duplicated per-d slot pair);
// block 16 computes wsq (fp64 -> fp32 once) and zeroes the tie counter.
// Wpp layout: [(c*512 + k)*32] shorts, c = d-chunk, k = code (global 0..511).
// ---------------------------------------------------------------------------
__global__ __launch_bounds__(512) void prep_kernel(const float* __restrict__ W,
                                                   unsigned short* __restrict__ Wpp,
                                                   float* __restrict__ wsq,
                                                   int* __restrict__ gcnt) {
    const int bx = blockIdx.x;
    const int k  = threadIdx.x;   // 0..511
    if (bx < NCH) {
        const int d0 = bx * DCH;
        float w[16];
        const float4* src4 = (const float4*)(W + (size_t)k * DD + d0);
        #pragma unroll
        for (int q = 0; q < 4; ++q) {
            float4 v = src4[q];
            w[4 * q + 0] = v.x; w[4 * q + 1] = v.y; w[4 * q + 2] = v.z; w[4 * q + 3] = v.w;
        }
        __align__(16) unsigned int dw[16];
        #pragma unroll
        for (int j = 0; j < 16; ++j) {
            unsigned short s = f16bits(w[j] * 4096.0f);  // exact pow2 scale, then RNE
            dw[j] = (unsigned int)s | ((unsigned int)s << 16);  // (wh, wh) slot pair
        }
        unsigned short* dst = Wpp + ((size_t)bx * 512 + k) * 32;
        #pragma unroll
        for (int j = 0; j < 4; ++j) ((int4*)dst)[j] = ((const int4*)dw)[j];
    } else {
        const float4* row = (const float4*)(W + (size_t)k * DD);
        double s = 0.0;
        #pragma unroll 8
        for (int i = 0; i < DD / 4; ++i) {
            float4 v = row[i];
            s += (double)v.x * v.x + (double)v.y * v.y + (double)v.z * v.z + (double)v.w * v.w;
        }
        wsq[k] = (float)s;
        if (k == 0) *gcnt = 0;
    }
}

// ---------------------------------------------------------------------------
// Prep Z (tier-big): one thread per token. Reads Z column (coalesced across
// lanes), computes zsq with the EXACT fp64 chain of the validated kernel
// (4 partials over sequential 64-d segments, (float)(((p0+p1)+p2)+p3)),
// and writes the (zh,zl) split row of 512 shorts, pre-swizzled in-row by
// byte XOR ((t&7)<<4) so vq_phase1 can global_load_lds linearly and
// ds_read_b128 conflict-free with the matching XOR.
// ---------------------------------------------------------------------------
__global__ __launch_bounds__(256) void prep_z(const float* __restrict__ Z,
                                              unsigned short* __restrict__ Zt,
                                              float* __restrict__ zsq) {
    const int tid = threadIdx.x;
    const int bt  = blockIdx.x * 256 + tid;         // global token id
    const int bb  = bt >> 12;
    const int t   = bt & 4095;

    const float* zc = Z + (size_t)bb * DD * NT + t;
    char* row = (char*)Zt + ((size_t)bt << 10);     // 1024 B per token
    const int swz = (t & 7) << 4;                   // byte swizzle within row

    double p[4];
    #pragma unroll
    for (int seg = 0; seg < 4; ++seg) {
        double s = 0.0;
        #pragma unroll
        for (int g = 0; g < 8; ++g) {
            const int d0 = seg * 64 + g * 8;
            float zv[8];
            #pragma unroll
            for (int j = 0; j < 8; ++j)
                zv[j] = zc[(size_t)(d0 + j) * NT];
            #pragma unroll
            for (int j = 0; j < 8; ++j)
                s = fma((double)zv[j], (double)zv[j], s);
            __align__(16) unsigned int u[8];
            #pragma unroll
            for (int j = 0; j < 8; ++j) {
                float z = zv[j];
                _Float16 zh = (_Float16)z;
                float rz = z - (float)zh;           // exact (Sterbenz)
                unsigned short hs, ls;
                __builtin_memcpy(&hs, &zh, 2);
                ls = f16bits(rz);
                u[j] = (unsigned int)hs | ((unsigned int)ls << 16);  // (zh, zl)
            }
            // two int4 stores, byte position (d*4) ^ swz (swz hits bits 4-6)
            *(int4*)(row + (((d0 * 4) + 0) ^ swz))  = ((const int4*)u)[0];
            *(int4*)(row + (((d0 * 4) + 16) ^ swz)) = ((const int4*)u)[1];
        }
        p[seg] = s;
    }
    zsq[bt] = (float)(((p[0] + p[1]) + p[2]) + p[3]);
}

// ---------------------------------------------------------------------------
// Phase 1 (tier-big): block = 64 t x ALL 512 codes, 256 thr, 4 waves.
// A staged by pure global_load_lds DMA (64 rows x 1 KB, linear LDS, source
// pre-swizzled by prep_z); frag ds_read applies the matching XOR -> 8-way
// uniform 16B distribution = conflict-free b128. B (Wpp) register-prefetched
// from L2 with named static double buffers. Zero VALU staging, zero fp64.
// acc inputs bit-identical to the validated chain.
// ---------------------------------------------------------------------------
__global__ __launch_bounds__(256, 2) void vq_phase1_gl(const unsigned short* __restrict__ Zt,
                                                       const float* __restrict__ zsqg,
                                                       const unsigned short* __restrict__ Wpp,
                                                       const float* __restrict__ wsq,
                                                       int* __restrict__ out,
                                                       int* __restrict__ gties,
                                                       int* __restrict__ gcnt) {
    __shared__ __align__(16) short As[64 * 512];    // 65,536 B, linear rows
    __shared__ int lcnt, gbase;

    const int tid  = threadIdx.x;
    const int wave = tid >> 6;
    const int lane = tid & 63;
    const int lm   = lane & 15;
    const int lq   = lane >> 4;
    const int nw   = wave;        // k quarter (128 codes)

    const int bx  = blockIdx.x;
    const int bt0 = bx * 64;      // global token base (b*4096 + t0)
    const int b   = bx >> 6;
    const int t0  = (bx & 63) * 64;

    if (tid == 0) lcnt = 0;

    // ---- A staging: 16 global_load_lds per wave (rows wave*16 + i)
    {
        const char* zbase = (const char*)Zt + ((size_t)bt0 << 10);
        #pragma unroll
        for (int i = 0; i < 16; ++i) {
            const int row = wave * 16 + i;
            gl_lds16(zbase + ((size_t)row << 10) + ((size_t)lane << 4),
                     &As[row * 512]);
        }
    }
    __syncthreads();   // drains vmcnt; the ONLY pre-epilogue barrier

    // ---- B fragment base: lane reads 16 B of code (nw*128 + nt*16 + lm)
    const unsigned short* wb = Wpp + ((size_t)(nw * 128 + lm) * 32) + lq * 8;

    f32x4 acc[4][8];
    #pragma unroll
    for (int mt = 0; mt < 4; ++mt)
        #pragma unroll
        for (int nt = 0; nt < 8; ++nt)
            acc[mt][nt] = (f32x4){0.f, 0.f, 0.f, 0.f};

    // A-frag read helper index: shorts, with XOR swizzle matching prep_z
    // addr = (mt*16+lm)*512 + ((c*32 + lq*8) ^ ((lm&7)<<3))
    int4 bvA[8], bvB[8];
    #pragma unroll
    for (int nt = 0; nt < 8; ++nt)
        bvA[nt] = *(const int4*)(wb + nt * 512);

    #pragma unroll
    for (int i = 0; i < 8; ++i) {
        const int cA = 2 * i, cB = 2 * i + 1;
        // prefetch chunk cB into bvB
        {
            const unsigned short* wp = wb + (size_t)cB * 16384;
            #pragma unroll
            for (int nt = 0; nt < 8; ++nt)
                bvB[nt] = *(const int4*)(wp + nt * 512);
        }
        // compute chunk cA with bvA
        {
            f16x8 a[4];
            #pragma unroll
            for (int mt = 0; mt < 4; ++mt)
                a[mt] = *(const f16x8*)&As[(mt * 16 + lm) * 512 +
                                           ((cA * 32 + lq * 8) ^ ((lm & 7) << 3))];
            #pragma unroll
            for (int mt = 0; mt < 4; ++mt)
                #pragma unroll
                for (int nt = 0; nt < 8; ++nt)
                    acc[mt][nt] = __builtin_amdgcn_mfma_f32_16x16x32_f16(
                        a[mt], *(const f16x8*)&bvA[nt], acc[mt][nt], 0, 0, 0);
        }
        // prefetch chunk cB+1 into bvA
        if (i < 7) {
            const unsigned short* wp = wb + (size_t)(cB + 1) * 16384;
            #pragma unroll
            for (int nt = 0; nt < 8; ++nt)
                bvA[nt] = *(const int4*)(wp + nt * 512);
        }
        // compute chunk cB with bvB
        {
            f16x8 a[4];
            #pragma unroll
            for (int mt = 0; mt < 4; ++mt)
                a[mt] = *(const f16x8*)&As[(mt * 16 + lm) * 512 +
                                           ((cB * 32 + lq * 8) ^ ((lm & 7) << 3))];
            #pragma unroll
            for (int mt = 0; mt < 4; ++mt)
                #pragma unroll
                for (int nt = 0; nt < 8; ++nt)
                    acc[mt][nt] = __builtin_amdgcn_mfma_f32_16x16x32_f16(
                        a[mt], *(const f16x8*)&bvB[nt], acc[mt][nt], 0, 0, 0);
        }
    }

    // ---- epilogue: chain, per-t top-2 (zsq precomputed, bit-identical)
    __syncthreads();                       // all A reads done; reuse As
    float* cb1   = (float*)As;             // [64][4]
    float* cb2   = (float*)(As + 512);
    int*   cbi   = (int*)(As + 1024);
    int*   llist = (int*)(As + 1536);      // 64 ints

    float wq[8];
    #pragma unroll
    for (int nt = 0; nt < 8; ++nt)
        wq[nt] = wsq[nw * 128 + nt * 16 + lm];
    const int kbase = nw * 128 + lm;

    #pragma unroll
    for (int mt = 0; mt < 4; ++mt) {
        #pragma unroll
        for (int r = 0; r < 4; ++r) {
            float zz = zsqg[bt0 + mt * 16 + lq * 4 + r];
            float q1 = INFINITY, q2 = INFINITY;
            int i1 = 0x7fffffff;
            #pragma unroll
            for (int nt = 0; nt < 8; ++nt) {
                // acc holds cross*2^12; fl(2*cross) = acc * 2^-11 (exact pow2)
                float c2   = __fmul_rn(acc[mt][nt][r], 4.8828125e-4f);
                float dist = __fadd_rn(__fsub_rn(zz, c2), wq[nt]);
                int kk = kbase + nt * 16;
                if (dist < q1 || (dist == q1 && kk < i1)) { q2 = q1; q1 = dist; i1 = kk; }
                else if (dist < q2) q2 = dist;
            }
            #pragma unroll
            for (int mk = 1; mk <= 8; mk <<= 1) {
                float o1 = __shfl_xor(q1, mk);
                float o2 = __shfl_xor(q2, mk);
                int   oi = __shfl_xor(i1, mk);
                if (o1 < q1 || (o1 == q1 && oi < i1)) { q2 = fminf(q1, o2); q1 = o1; i1 = oi; }
                else { q2 = fminf(o1, q2); }
            }
            if (lm == 0) {
                int m = mt * 16 + lq * 4 + r;
                cb1[m * 4 + nw] = q1;
                cb2[m * 4 + nw] = q2;
                cbi[m * 4 + nw] = i1;
            }
        }
    }
    __syncthreads();
    if (tid < 64) {
        float q1 = cb1[tid * 4], q2 = cb2[tid * 4];
        int   i1 = cbi[tid * 4];
        #pragma unroll
        for (int p = 1; p < 4; ++p) {
            float c1 = cb1[tid * 4 + p], c2v = cb2[tid * 4 + p];
            int   ci = cbi[tid * 4 + p];
            if (c1 < q1 || (c1 == q1 && ci < i1)) { q2 = fminf(q1, c2v); q1 = c1; i1 = ci; }
            else { q2 = fminf(q2, c1); }
        }
        out[bt0 + tid] = i1;
        if (q2 - q1 <= MARGIN) {
            int p = atomicAdd(&lcnt, 1);
            llist[p] = bt0 + tid;               // global bt id
        }
    }
    __syncthreads();
    if (tid == 0) gbase = (lcnt > 0) ? atomicAdd(gcnt, lcnt) : 0;
    __syncthreads();
    if (tid < lcnt) gties[gbase + tid] = llist[tid];
}

// ---------------------------------------------------------------------------
// Phase 1 (tier-2, R2-validated fallback when ws < 136 MB): barrier-free
// main loop, in-kernel f16 split + fp64 zsq. Unchanged from round 2.
// ---------------------------------------------------------------------------
__global__ __launch_bounds__(256, 2) void vq_phase1_reg(const float* __restrict__ Z,
                                                        const unsigned short* __restrict__ Wpp,
                                                        const float* __restrict__ wsq,
                                                        int* __restrict__ out,
                                                        int* __restrict__ gties,
                                                        int* __restrict__ gcnt) {
    __shared__ __align__(16) short As[64 * ASTR];   // 68,608 B
    __shared__ int lcnt, gbase;

    const int tid  = threadIdx.x;
    const int wave = tid >> 6;
    const int lane = tid & 63;
    const int lm   = lane & 15;
    const int lq   = lane >> 4;
    const int nw   = wave;

    const int bx = blockIdx.x;
    const int b  = bx >> 6;
    const int t0 = (bx & 63) * 64;

    const int t_l = tid & 63;
    const int dgs = tid >> 6;

    const float* zcol = Z + (size_t)b * DD * NT + t0 + t_l;

    if (tid == 0) lcnt = 0;

    double zacc = 0.0;
    #pragma unroll
    for (int half = 0; half < 2; ++half) {
        float zv[32];
        #pragma unroll
        for (int j = 0; j < 32; ++j)
            zv[j] = zcol[(size_t)(dgs * 64 + half * 32 + j) * NT];
        #pragma unroll
        for (int j = 0; j < 32; ++j)
            zacc = fma((double)zv[j], (double)zv[j], zacc);
        #pragma unroll
        for (int j0 = 0; j0 < 32; j0 += 4) {
            __align__(16) unsigned int u[4];
            #pragma unroll
            for (int q = 0; q < 4; ++q) {
                float z = zv[j0 + q];
                _Float16 zh = (_Float16)z;
                float rz = z - (float)zh;
                unsigned short hs, ls;
                __builtin_memcpy(&hs, &zh, 2);
                ls = f16bits(rz);
                u[q] = (unsigned int)hs | ((unsigned int)ls << 16);
            }
            *(int4*)&As[t_l * ASTR + (dgs * 64 + half * 32 + j0) * 2] = *(const int4*)u;
        }
    }
    __syncthreads();

    const unsigned short* wb = Wpp + ((size_t)(nw * 128 + lm) * 32) + lq * 8;

    f32x4 acc[4][8];
    #pragma unroll
    for (int mt = 0; mt < 4; ++mt)
        #pragma unroll
        for (int nt = 0; nt < 8; ++nt)
            acc[mt][nt] = (f32x4){0.f, 0.f, 0.f, 0.f};

    int4 bv0[8], bv1[8];
    #pragma unroll
    for (int nt = 0; nt < 8; ++nt)
        bv0[nt] = *(const int4*)(wb + nt * 512);

    #pragma unroll
    for (int c = 0; c < NCH; ++c) {
        int4* cur = (c & 1) ? bv1 : bv0;
        int4* nxt = (c & 1) ? bv0 : bv1;
        if (c < NCH - 1) {
            const unsigned short* wp = wb + (size_t)(c + 1) * 16384;
            #pragma unroll
            for (int nt = 0; nt < 8; ++nt)
                nxt[nt] = *(const int4*)(wp + nt * 512);
        }
        f16x8 a[4];
        #pragma unroll
        for (int mt = 0; mt < 4; ++mt)
            a[mt] = *(const f16x8*)&As[(mt * 16 + lm) * ASTR + c * 32 + lq * 8];
        #pragma unroll
        for (int mt = 0; mt < 4; ++mt)
            #pragma unroll
            for (int nt = 0; nt < 8; ++nt)
                acc[mt][nt] = __builtin_amdgcn_mfma_f32_16x16x32_f16(
                    a[mt], *(const f16x8*)&cur[nt], acc[mt][nt], 0, 0, 0);
    }

    __syncthreads();
    double* zred = (double*)As;
    float*  zf   = (float*)(As + 1024);
    float*  cb1  = (float*)(As + 1536);
    float*  cb2  = (float*)(As + 2048);
    int*    cbi  = (int*)(As + 2560);
    int*    llist = (int*)(As + 3072);

    zred[dgs * 64 + t_l] = zacc;
    __syncthreads();
    if (tid < 64) {
        double s = zred[tid];
        #pragma unroll
        for (int p = 1; p < 4; ++p) s += zred[p * 64 + tid];
        zf[tid] = (float)s;
    }
    __syncthreads();

    float wq[8];
    #pragma unroll
    for (int nt = 0; nt < 8; ++nt)
        wq[nt] = wsq[nw * 128 + nt * 16 + lm];
    const int kbase = nw * 128 + lm;

    #pragma unroll
    for (int mt = 0; mt < 4; ++mt) {
        #pragma unroll
        for (int r = 0; r < 4; ++r) {
            float zz = zf[mt * 16 + lq * 4 + r];
            float q1 = INFINITY, q2 = INFINITY;
            int i1 = 0x7fffffff;
            #pragma unroll
            for (int nt = 0; nt < 8; ++nt) {
                float c2   = __fmul_rn(acc[mt][nt][r], 4.8828125e-4f);
                float dist = __fadd_rn(__fsub_rn(zz, c2), wq[nt]);
                int kk = kbase + nt * 16;
                if (dist < q1 || (dist == q1 && kk < i1)) { q2 = q1; q1 = dist; i1 = kk; }
                else if (dist < q2) q2 = dist;
            }
            #pragma unroll
            for (int mk = 1; mk <= 8; mk <<= 1) {
                float o1 = __shfl_xor(q1, mk);
                float o2 = __shfl_xor(q2, mk);
                int   oi = __shfl_xor(i1, mk);
                if (o1 < q1 || (o1 == q1 && oi < i1)) { q2 = fminf(q1, o2); q1 = o1; i1 = oi; }
                else { q2 = fminf(o1, q2); }
            }
            if (lm == 0) {
                int m = mt * 16 + lq * 4 + r;
                cb1[m * 4 + nw] = q1;
                cb2[m * 4 + nw] = q2;
                cbi[m * 4 + nw] = i1;
            }
        }
    }
    __syncthreads();
    if (tid < 64) {
        float q1 = cb1[tid * 4], q2 = cb2[tid * 4];
        int   i1 = cbi[tid * 4];
        #pragma unroll
        for (int p = 1; p < 4; ++p) {
            float c1 = cb1[tid * 4 + p], c2v = cb2[tid * 4 + p];
            int   ci = cbi[tid * 4 + p];
            if (c1 < q1 || (c1 == q1 && ci < i1)) { q2 = fminf(q1, c2v); q1 = c1; i1 = ci; }
            else { q2 = fminf(q2, c1); }
        }
        out[(size_t)b * NT + t0 + tid] = i1;
        if (q2 - q1 <= MARGIN) {
            int p = atomicAdd(&lcnt, 1);
            llist[p] = b * NT + t0 + tid;
        }
    }
    __syncthreads();
    if (tid == 0) gbase = (lcnt > 0) ? atomicAdd(gcnt, lcnt) : 0;
    __syncthreads();
    if (tid < lcnt) gties[gbase + tid] = llist[tid];
}

// ---------------------------------------------------------------------------
// Tie fix: reads the global tie list; recomputes listed tokens exactly
// (identical fp32 chain / fmaf order as the validated kernel) in batches of 8.
// ---------------------------------------------------------------------------
__global__ __launch_bounds__(256) void vq_fix(const float* __restrict__ Z,
                                              const float* __restrict__ W,
                                              const float* __restrict__ wsq,
                                              const int* __restrict__ gties,
                                              const int* __restrict__ gcnt,
                                              int* __restrict__ out) {
    __shared__ __align__(16) float Zs[8][256];
    __shared__ double pz[8][32];
    __shared__ float  zsqs[8];
    __shared__ int    bts[8];
    __shared__ float  rv[8][4];
    __shared__ int    ri[8][4];

    const int tid  = threadIdx.x;
    const int lane = tid & 63;
    const int wvx  = tid >> 6;
    const int n    = *gcnt;

    for (int base = blockIdx.x * 8; base < n; base += (int)gridDim.x * 8) {
        const int m = (n - base < 8) ? (n - base) : 8;
        __syncthreads();
        if (tid < 8) bts[tid] = gties[base + ((tid < m) ? tid : 0)];
        __syncthreads();

        #pragma unroll
        for (int i = 0; i < 8; ++i) {
            if (i < m) {
                int tb = bts[i];
                int bb = tb >> 12, t = tb & 4095;
                Zs[i][tid] = Z[(size_t)bb * DD * NT + (size_t)tid * NT + t];
            }
        }
        __syncthreads();

        {
            int i = tid >> 5, seg = tid & 31;
            double s = 0.0;
            #pragma unroll
            for (int j = 0; j < 8; ++j) {
                double zz = (double)Zs[i][seg * 8 + j];
                s = fma(zz, zz, s);
            }
            pz[i][seg] = s;
        }
        __syncthreads();
        if (tid < 8) {
            double s = 0.0;
            #pragma unroll
            for (int j = 0; j < 32; ++j) s += pz[tid][j];
            zsqs[tid] = (float)s;
        }
        __syncthreads();

        float da[2][8];
        #pragma unroll
        for (int rr = 0; rr < 2; ++rr) {
            int k = tid + rr * 256;
            const float4* wr = (const float4*)(W + (size_t)k * DD);
            float a8[8];
            #pragma unroll
            for (int i = 0; i < 8; ++i) a8[i] = 0.f;
            #pragma unroll 2
            for (int q = 0; q < 64; ++q) {
                float4 w4 = wr[q];
                #pragma unroll
                for (int i = 0; i < 8; ++i) {
                    float4 z4 = *(const float4*)&Zs[i][4 * q];   // LDS broadcast
                    a8[i] = fmaf(z4.x, w4.x, a8[i]);
                    a8[i] = fmaf(z4.y, w4.y, a8[i]);
                    a8[i] = fmaf(z4.z, w4.z, a8[i]);
                    a8[i] = fmaf(z4.w, w4.w, a8[i]);
                }
            }
            float wqv = wsq[k];
            #pragma unroll
            for (int i = 0; i < 8; ++i)
                da[rr][i] = __fadd_rn(__fsub_rn(zsqs[i], __fmul_rn(2.0f, a8[i])), wqv);
        }

        #pragma unroll
        for (int i = 0; i < 8; ++i) {
            float v = da[0][i]; int ix = tid;
            if (da[1][i] < v) { v = da[1][i]; ix = tid + 256; }
            #pragma unroll
            for (int mk = 1; mk <= 32; mk <<= 1) {
                float ov = __shfl_xor(v, mk);
                int   oi = __shfl_xor(ix, mk);
                if (ov < v || (ov == v && oi < ix)) { v = ov; ix = oi; }
            }
            if (lane == 0) { rv[i][wvx] = v; ri[i][wvx] = ix; }
        }
        __syncthreads();
        if (tid < 8 && tid < m) {
            float v = INFINITY; int ix = 0x7fffffff;
            #pragma unroll
            for (int w = 0; w < 4; ++w) {
                if (rv[tid][w] < v || (rv[tid][w] == v && ri[tid][w] < ix)) {
                    v = rv[tid][w]; ix = ri[tid][w];
                }
            }
            out[bts[tid]] = ix;
        }
    }
}

// ---------------------------------------------------------------------------
// Fallback (R1 kernel) if ws is too small.
// ---------------------------------------------------------------------------
#define BT 128
#define BK 128
#define DCHUNK 32
#define NKC (NK / BK)
#define NDC (DD / DCHUNK)
#define WSTR (BK + 4)

__global__ __launch_bounds__(256) void vq_fallback(const float* __restrict__ Z,
                                                   const float* __restrict__ W,
                                                   int* __restrict__ out) {
    __shared__ __align__(16) float Zs[DCHUNK * BT];
    __shared__ __align__(16) float Ws[DCHUNK * WSTR];
    __shared__ float wsqs[NK];

    const int tid = threadIdx.x;
    const int tx  = tid & 15;
    const int ty  = tid >> 4;
    const int b   = blockIdx.y;
    const int t0  = blockIdx.x * BT;

    for (int k = tid; k < NK; k += 256) {
        const float4* row = (const float4*)(W + (size_t)k * DD);
        double s = 0.0;
        for (int i = 0; i < DD / 4; ++i) {
            float4 v = row[i];
            s += (double)v.x * v.x + (double)v.y * v.y + (double)v.z * v.z + (double)v.w * v.w;
        }
        wsqs[k] = (float)s;
    }

    const float* Zb = Z + (size_t)b * DD * NT + t0;

    float best[8]; int bidx[8];
    #pragma unroll
    for (int a = 0; a < 8; ++a) { best[a] = INFINITY; bidx[a] = 0x7fffffff; }
    double zsqd[8];
    #pragma unroll
    for (int a = 0; a < 8; ++a) zsqd[a] = 0.0;
    float zsqf[8];

    for (int kc = 0; kc < NKC; ++kc) {
        float acc[8][8];
        #pragma unroll
        for (int a = 0; a < 8; ++a)
            #pragma unroll
            for (int c = 0; c < 8; ++c) acc[a][c] = 0.f;

        for (int dc = 0; dc < NDC; ++dc) {
            const int d0 = dc * DCHUNK;
            __syncthreads();
            #pragma unroll
            for (int i = 0; i < 4; ++i) {
                int f  = tid + i * 256;
                int r  = f >> 5;
                int c4 = f & 31;
                float4 v = *(const float4*)(Zb + (size_t)(d0 + r) * NT + c4 * 4);
                *(float4*)(&Zs[r * BT + c4 * 4]) = v;
            }
            #pragma unroll
            for (int i = 0; i < 4; ++i) {
                int u  = tid + i * 256;
                int k  = u >> 3;
                int rg = u & 7;
                float4 v = *(const float4*)(W + (size_t)(kc * BK + k) * DD + d0 + rg * 4);
                Ws[(rg * 4 + 0) * WSTR + k] = v.x;
                Ws[(rg * 4 + 1) * WSTR + k] = v.y;
                Ws[(rg * 4 + 2) * WSTR + k] = v.z;
                Ws[(rg * 4 + 3) * WSTR + k] = v.w;
            }
            __syncthreads();
            #pragma unroll 4
            for (int d = 0; d < DCHUNK; ++d) {
                float4 z0 = *(const float4*)(&Zs[d * BT + ty * 8]);
                float4 z1 = *(const float4*)(&Zs[d * BT + ty * 8 + 4]);
                float4 w0 = *(const float4*)(&Ws[d * WSTR + tx * 8]);
                float4 w1 = *(const float4*)(&Ws[d * WSTR + tx * 8 + 4]);
                float za[8] = {z0.x, z0.y, z0.z, z0.w, z1.x, z1.y, z1.z, z1.w};
                float wa[8] = {w0.x, w0.y, w0.z, w0.w, w1.x, w1.y, w1.z, w1.w};
                if (kc == 0) {
                    #pragma unroll
                    for (int a = 0; a < 8; ++a)
                        zsqd[a] = fma((double)za[a], (double)za[a], zsqd[a]);
                }
                #pragma unroll
                for (int a = 0; a < 8; ++a)
                    #pragma unroll
                    for (int c = 0; c < 8; ++c)
                        acc[a][c] = fmaf(za[a], wa[c], acc[a][c]);
            }
        }
        if (kc == 0) {
            #pragma unroll
            for (int a = 0; a < 8; ++a) zsqf[a] = (float)zsqd[a];
        }
        #pragma unroll
        for (int c = 0; c < 8; ++c) {
            int   kg = kc * BK + tx * 8 + c;
            float wqv = wsqs[kg];
            #pragma unroll
            for (int a = 0; a < 8; ++a) {
                float c2   = __fmul_rn(2.0f, acc[a][c]);
                float s    = __fsub_rn(zsqf[a], c2);
                float dist = __fadd_rn(s, wqv);
                if (dist < best[a] || (dist == best[a] && kg < bidx[a])) {
                    best[a] = dist; bidx[a] = kg;
                }
            }
        }
    }
    __syncthreads();
    float* redv = Zs;
    int*   redi = (int*)Ws;
    #pragma unroll
    for (int a = 0; a < 8; ++a) {
        int tl2 = ty * 8 + a;
        redv[tl2 * 16 + tx] = best[a];
        redi[tl2 * 16 + tx] = bidx[a];
    }
    __syncthreads();
    if (tid < BT) {
        float bv = INFINITY; int bi = 0x7fffffff;
        #pragma unroll
        for (int j = 0; j < 16; ++j) {
            float v = redv[tid * 16 + j];
            int   i = redi[tid * 16 + j];
            if (v < bv || (v == bv && i < bi)) { bv = v; bi = i; }
        }
        out[(size_t)b * NT + t0 + tid] = bi;
    }
}

extern "C" void kernel_launch(void* const* d_in, const int* in_sizes, int n_in,
                              void* d_out, int out_size, void* d_ws, size_t ws_size,
                              hipStream_t stream) {
    const float* Z = (const float*)d_in[0];   // [B, D, T]
    const float* W = (const float*)d_in[1];   // [K, D]
    int* out = (int*)d_out;                   // [B, T]

    // ---- tier-big layout (needs ~136 MB)
    const size_t OFF_WSQ = 0;                          // 512 f32
    const size_t OFF_CNT = 2048;                       // tie counter
    const size_t OFF_ZSQ = 4096;                       // 131072 f32 (512 KB)
    const size_t OFF_WPP = OFF_ZSQ + 524288;           // 512 KB
    const size_t OFF_TIE = OFF_WPP + 524288;           // up to 131072 ints
    const size_t OFF_ZT  = OFF_TIE + 524288;           // 128 MB split-f16 Z
    const size_t NEED_BIG = OFF_ZT + 134217728;        // 135,794,688 B

    // ---- tier-2 layout (R2 path, ~1.05 MB)
    const size_t T2_WSQ = 0;
    const size_t T2_CNT = 2048;
    const size_t T2_WPP = 4096;
    const size_t T2_TIE = T2_WPP + 524288;
    const size_t NEED_T2 = T2_TIE + 524288;            // 1,052,672 B

    if (ws_size >= NEED_BIG) {
        float* wsq  = (float*)((char*)d_ws + OFF_WSQ);
        int*   gcnt = (int*)((char*)d_ws + OFF_CNT);
        float* zsq  = (float*)((char*)d_ws + OFF_ZSQ);
        unsigned short* wpp = (unsigned short*)((char*)d_ws + OFF_WPP);
        int*   gties = (int*)((char*)d_ws + OFF_TIE);
        unsigned short* zt = (unsigned short*)((char*)d_ws + OFF_ZT);

        prep_kernel<<<dim3(NCH + 1), dim3(512), 0, stream>>>(W, wpp, wsq, gcnt);
        prep_z<<<dim3(512), dim3(256), 0, stream>>>(Z, zt, zsq);
        vq_phase1_gl<<<dim3(2048), dim3(256), 0, stream>>>(zt, zsq, wpp, wsq, out, gties, gcnt);
        vq_fix<<<dim3(256), dim3(256), 0, stream>>>(Z, W, wsq, gties, gcnt, out);
    } else if (ws_size >= NEED_T2) {
        float* wsq  = (float*)((char*)d_ws + T2_WSQ);
        int*   gcnt = (int*)((char*)d_ws + T2_CNT);
        unsigned short* wpp = (unsigned short*)((char*)d_ws + T2_WPP);
        int*   gties = (int*)((char*)d_ws + T2_TIE);

        prep_kernel<<<dim3(NCH + 1), dim3(512), 0, stream>>>(W, wpp, wsq, gcnt);
        vq_phase1_reg<<<dim3(2048), dim3(256), 0, stream>>>(Z, wpp, wsq, out, gties, gcnt);
        vq_fix<<<dim3(256), dim3(256), 0, stream>>>(Z, W, wsq, gties, gcnt, out);
    } else {
        vq_fallback<<<dim3(NT / BT, NB), dim3(256), 0, stream>>>(Z, W, out);
    }
}

// Round 4
// 337.859 us; speedup vs baseline: 1.4403x; 1.4403x over previous
//
#include <hip/hip_runtime.h>
#include <math.h>

#define NK 512
#define DD 256
#define NB 32
#define NT 4096

typedef __attribute__((ext_vector_type(8))) _Float16 f16x8;
typedef __attribute__((ext_vector_type(4))) float f32x4;

#define MARGIN 1.5e-4f
#define DCH 16      // d per chunk
#define NCH 16      // chunks (DD/DCH)
#define ASTR 536    // LDS row stride in shorts (1072 B: 268 dw, 268%32=12 -> 2-way max)
#define ZCROWS 65536       // Zc capacity (tokens); overflow -> guarded full fix
#define PCAP   524288      // global pair capacity
#define PBCAP  8192        // per-block pair list capacity (LDS overlay)

__device__ __forceinline__ unsigned short f16bits(float x) {
    _Float16 h = (_Float16)x;           // v_cvt_f16_f32, RNE
    unsigned short s;
    __builtin_memcpy(&s, &h, 2);
    return s;
}

// ---------------------------------------------------------------------------
// Prep W: blocks 0..15 build Wpp (f16 w*4096, duplicated per-d slot pair);
// block 16 computes wsq (fp64 -> fp32 once) and zeroes counters.
// ---------------------------------------------------------------------------
__global__ __launch_bounds__(512) void prep_kernel(const float* __restrict__ W,
                                                   unsigned short* __restrict__ Wpp,
                                                   float* __restrict__ wsq,
                                                   int* __restrict__ gcnt,
                                                   int* __restrict__ pcnt,
                                                   int* __restrict__ oflow) {
    const int bx = blockIdx.x;
    const int k  = threadIdx.x;   // 0..511
    if (bx < NCH) {
        const int d0 = bx * DCH;
        float w[16];
        const float4* src4 = (const float4*)(W + (size_t)k * DD + d0);
        #pragma unroll
        for (int q = 0; q < 4; ++q) {
            float4 v = src4[q];
            w[4 * q + 0] = v.x; w[4 * q + 1] = v.y; w[4 * q + 2] = v.z; w[4 * q + 3] = v.w;
        }
        __align__(16) unsigned int dw[16];
        #pragma unroll
        for (int j = 0; j < 16; ++j) {
            unsigned short s = f16bits(w[j] * 4096.0f);  // exact pow2 scale, then RNE
            dw[j] = (unsigned int)s | ((unsigned int)s << 16);  // (wh, wh) slot pair
        }
        unsigned short* dst = Wpp + ((size_t)bx * 512 + k) * 32;
        #pragma unroll
        for (int j = 0; j < 4; ++j) ((int4*)dst)[j] = ((const int4*)dw)[j];
    } else {
        const float4* row = (const float4*)(W + (size_t)k * DD);
        double s = 0.0;
        #pragma unroll 8
        for (int i = 0; i < DD / 4; ++i) {
            float4 v = row[i];
            s += (double)v.x * v.x + (double)v.y * v.y + (double)v.z * v.z + (double)v.w * v.w;
        }
        wsq[k] = (float)s;
        if (k == 0) *gcnt = 0;
        if (k == 1) *pcnt = 0;
        if (k == 2) *oflow = 0;
    }
}

// ---------------------------------------------------------------------------
// Phase 1 (big tier): 512 thr / 8 waves; block = 64 t x 512 codes; each wave
// owns 64t x 64c -> acc[4][4] (64 AGPR). __launch_bounds__(512,4) => <=128
// regs => 2 blocks/CU = 16 waves/CU. Staging (threads 0..255) keeps the exact
// 64-d fp64 chains of the validated kernel; K-loop barrier-free, B from L2
// with named double buffers. All dist bits identical to the validated chain.
// Epilogue: top-2 -> out + tie list; tie tokens get (a) Z column copied to a
// compact fp32 buffer, (b) old-fix-chain zsq, (c) candidate pairs
// {k : d_approx <= q1+MARGIN} appended globally.
// ---------------------------------------------------------------------------
__global__ __launch_bounds__(512, 4) void vq_phase1(const float* __restrict__ Z,
                                                    const unsigned short* __restrict__ Wpp,
                                                    const float* __restrict__ wsq,
                                                    int* __restrict__ out,
                                                    int* __restrict__ gties,
                                                    int* __restrict__ gcnt,
                                                    float* __restrict__ Zc,
                                                    float* __restrict__ zq,
                                                    unsigned long long* __restrict__ slots,
                                                    int* __restrict__ gpairs,
                                                    int* __restrict__ pcnt,
                                                    int* __restrict__ oflow) {
    __shared__ __align__(16) short As[64 * ASTR];   // 68,608 B
    __shared__ int lcnt, gbase, pcl, pbase_sh, pcl_sh;

    const int tid  = threadIdx.x;
    const int wave = tid >> 6;
    const int lane = tid & 63;
    const int lm   = lane & 15;
    const int lq   = lane >> 4;
    const int nw   = wave;        // k-eighth (64 codes)

    const int bx = blockIdx.x;
    const int b  = bx >> 6;
    const int t0 = (bx & 63) * 64;

    const int t_l = tid & 63;
    const int dgs = (tid >> 6) & 3;   // staging segment for tid<256

    if (tid == 0) { lcnt = 0; pcl = 0; }

    // ---- staging: threads 0..255, exact 64-d fp64 chain per thread
    double zacc = 0.0;
    if (tid < 256) {
        const float* zcol = Z + (size_t)b * DD * NT + t0 + t_l;
        #pragma unroll
        for (int g = 0; g < 8; ++g) {
            float zv[8];
            #pragma unroll
            for (int j = 0; j < 8; ++j)
                zv[j] = zcol[(size_t)(dgs * 64 + g * 8 + j) * NT];
            #pragma unroll
            for (int j = 0; j < 8; ++j)
                zacc = fma((double)zv[j], (double)zv[j], zacc);
            __align__(16) unsigned int u[8];
            #pragma unroll
            for (int j = 0; j < 8; ++j) {
                float z = zv[j];
                _Float16 zh = (_Float16)z;
                float rz = z - (float)zh;     // exact (Sterbenz)
                unsigned short hs, ls;
                __builtin_memcpy(&hs, &zh, 2);
                ls = f16bits(rz);
                u[j] = (unsigned int)hs | ((unsigned int)ls << 16);  // (zh, zl)
            }
            int4* dst = (int4*)&As[t_l * ASTR + dgs * 128 + g * 16];
            dst[0] = ((const int4*)u)[0];
            dst[1] = ((const int4*)u)[1];
        }
    }

    // ---- B fragment base (all waves); first-chunk prefetch pre-barrier
    const unsigned short* wb = Wpp + ((size_t)(nw * 64 + lm) * 32) + lq * 8;
    int4 bv0[4], bv1[4];
    #pragma unroll
    for (int nt = 0; nt < 4; ++nt)
        bv0[nt] = *(const int4*)(wb + nt * 512);

    __syncthreads();   // staging visible; the ONLY pre-epilogue barrier

    f32x4 acc[4][4];
    #pragma unroll
    for (int mt = 0; mt < 4; ++mt)
        #pragma unroll
        for (int nt = 0; nt < 4; ++nt)
            acc[mt][nt] = (f32x4){0.f, 0.f, 0.f, 0.f};

    #pragma unroll
    for (int c = 0; c < NCH; ++c) {
        int4* cur = (c & 1) ? bv1 : bv0;
        int4* nxt = (c & 1) ? bv0 : bv1;
        if (c < NCH - 1) {
            const unsigned short* wp = wb + (size_t)(c + 1) * 16384;
            #pragma unroll
            for (int nt = 0; nt < 4; ++nt)
                nxt[nt] = *(const int4*)(wp + nt * 512);
        }
        f16x8 a[4];
        #pragma unroll
        for (int mt = 0; mt < 4; ++mt)
            a[mt] = *(const f16x8*)&As[(mt * 16 + lm) * ASTR + c * 32 + lq * 8];
        #pragma unroll
        for (int mt = 0; mt < 4; ++mt)
            #pragma unroll
            for (int nt = 0; nt < 4; ++nt)
                acc[mt][nt] = __builtin_amdgcn_mfma_f32_16x16x32_f16(
                    a[mt], *(const f16x8*)&cur[nt], acc[mt][nt], 0, 0, 0);
    }

    // ---- epilogue. LDS overlay (As free after K-loop).
    __syncthreads();
    char* base = (char*)As;
    double* zred  = (double*)base;              // [4][64]  2048 B
    float*  zf    = (float*)(base + 2048);      // 64
    float*  qf    = (float*)(base + 2304);      // 64
    int*    tia   = (int*)(base + 2560);        // 64
    int*    ltok  = (int*)(base + 2816);        // 64
    float*  col   = (float*)(base + 3072);      // 256
    double* pzz   = (double*)(base + 4096);     // 32
    float*  cb1   = (float*)(base + 4608);      // [64][8]
    float*  cb2   = (float*)(base + 6656);
    int*    cbi   = (int*)(base + 8704);
    int*    plist = (int*)(base + 10752);       // PBCAP ints (32 KB)

    if (tid < 256) zred[dgs * 64 + t_l] = zacc;
    __syncthreads();
    if (tid < 64) {
        double s = zred[tid];
        #pragma unroll
        for (int p = 1; p < 4; ++p) s += zred[p * 64 + tid];
        zf[tid] = (float)s;
    }
    __syncthreads();

    float wq[4];
    #pragma unroll
    for (int nt = 0; nt < 4; ++nt)
        wq[nt] = wsq[nw * 64 + nt * 16 + lm];
    const int kbase = nw * 64 + lm;

    #pragma unroll
    for (int mt = 0; mt < 4; ++mt) {
        #pragma unroll
        for (int r = 0; r < 4; ++r) {
            float zz = zf[mt * 16 + lq * 4 + r];
            float q1 = INFINITY, q2 = INFINITY;
            int i1 = 0x7fffffff;
            #pragma unroll
            for (int nt = 0; nt < 4; ++nt) {
                // acc holds cross*2^12; fl(2*cross) = acc * 2^-11 (exact pow2)
                float c2   = __fmul_rn(acc[mt][nt][r], 4.8828125e-4f);
                float dist = __fadd_rn(__fsub_rn(zz, c2), wq[nt]);
                int kk = kbase + nt * 16;
                if (dist < q1 || (dist == q1 && kk < i1)) { q2 = q1; q1 = dist; i1 = kk; }
                else if (dist < q2) q2 = dist;
            }
            #pragma unroll
            for (int mk = 1; mk <= 8; mk <<= 1) {
                float o1 = __shfl_xor(q1, mk);
                float o2 = __shfl_xor(q2, mk);
                int   oi = __shfl_xor(i1, mk);
                if (o1 < q1 || (o1 == q1 && oi < i1)) { q2 = fminf(q1, o2); q1 = o1; i1 = oi; }
                else { q2 = fminf(o1, q2); }
            }
            if (lm == 0) {
                int m = mt * 16 + lq * 4 + r;
                cb1[m * 8 + nw] = q1;
                cb2[m * 8 + nw] = q2;
                cbi[m * 8 + nw] = i1;
            }
        }
    }
    __syncthreads();
    if (tid < 64) {
        float q1 = cb1[tid * 8], q2 = cb2[tid * 8];
        int   i1 = cbi[tid * 8];
        #pragma unroll
        for (int p = 1; p < 8; ++p) {
            float c1 = cb1[tid * 8 + p], c2v = cb2[tid * 8 + p];
            int   ci = cbi[tid * 8 + p];
            if (c1 < q1 || (c1 == q1 && ci < i1)) { q2 = fminf(q1, c2v); q1 = c1; i1 = ci; }
            else { q2 = fminf(q2, c1); }
        }
        out[(size_t)b * NT + t0 + tid] = i1;
        qf[tid] = q1;
        int ta = -1;
        if (q2 - q1 <= MARGIN) {
            ta = atomicAdd(&lcnt, 1);
            ltok[ta] = tid;
        }
        tia[tid] = ta;
    }
    __syncthreads();
    if (tid == 0) gbase = (lcnt > 0) ? atomicAdd(gcnt, lcnt) : 0;
    __syncthreads();

    // ---- tie-token Z copy (coalesced dest) + old-fix-chain zsq
    const int nloc = lcnt;
    for (int i = 0; i < nloc; ++i) {
        const int tok = ltok[i];
        const int ti  = gbase + i;
        if (ti < ZCROWS) {
            if (tid < 256) {
                float v = Z[(size_t)b * DD * NT + (size_t)tid * NT + (t0 + tok)];
                Zc[(size_t)ti * 256 + tid] = v;
                col[tid] = v;
            }
        } else if (tid == 0) {
            *oflow = 1;
        }
        if (tid == 0) {
            gties[ti] = b * NT + t0 + tok;
            slots[ti] = 0xFFFFFFFFFFFFFFFFULL;
        }
        __syncthreads();
        if (ti < ZCROWS) {
            if (tid < 32) {
                double s = 0.0;
                #pragma unroll
                for (int j = 0; j < 8; ++j) {
                    double zz = (double)col[tid * 8 + j];
                    s = fma(zz, zz, s);
                }
                pzz[tid] = s;
            }
        }
        __syncthreads();
        if (ti < ZCROWS && tid == 0) {
            double s = 0.0;
            #pragma unroll
            for (int j = 0; j < 32; ++j) s += pzz[j];
            zq[ti] = (float)s;
        }
        __syncthreads();
    }

    // ---- candidate pass: every lane re-tests its dists vs q1 + MARGIN
    if (nloc > 0) {
        #pragma unroll
        for (int mt = 0; mt < 4; ++mt) {
            #pragma unroll
            for (int r = 0; r < 4; ++r) {
                const int tok = mt * 16 + lq * 4 + r;
                const int ta  = tia[tok];
                if (ta < 0) continue;
                const int ti = gbase + ta;
                if (ti >= ZCROWS) continue;
                const float thr = qf[tok] + MARGIN;
                const float zz  = zf[tok];
                #pragma unroll
                for (int nt = 0; nt < 4; ++nt) {
                    float c2   = __fmul_rn(acc[mt][nt][r], 4.8828125e-4f);
                    float dist = __fadd_rn(__fsub_rn(zz, c2), wq[nt]);
                    if (dist <= thr) {
                        int p = atomicAdd(&pcl, 1);
                        if (p < PBCAP) plist[p] = (ti << 9) | (kbase + nt * 16);
                    }
                }
            }
        }
    }
    __syncthreads();
    if (tid == 0) {
        int take = pcl;
        int bs = (take > 0) ? atomicAdd(pcnt, take) : 0;
        pbase_sh = bs;
        pcl_sh = take;
        if (take > PBCAP || bs + take > PCAP) *oflow = 1;
    }
    __syncthreads();
    {
        int take = pcl_sh; if (take > PBCAP) take = PBCAP;
        for (int j = tid; j < take; j += 512) {
            int gp = pbase_sh + j;
            if (gp < PCAP) gpairs[gp] = plist[j];
        }
    }
}

// ---------------------------------------------------------------------------
// Pair fix: one thread per (tie-token, candidate-code) pair; exact fp32 fmaf
// chain (identical to the validated full fix); resolves winner per token via
// 64-bit atomicMin on (dist_bits<<32 | k)  (dist > 0 => bit order = value
// order; ties pick smaller k — exactly the validated comparator).
// ---------------------------------------------------------------------------
__global__ __launch_bounds__(256) void vq_fix_pairs(const float* __restrict__ W,
                                                    const float* __restrict__ wsq,
                                                    const float* __restrict__ Zc,
                                                    const float* __restrict__ zq,
                                                    const int* __restrict__ gpairs,
                                                    const int* __restrict__ pcnt,
                                                    unsigned long long* __restrict__ slots) {
    int np = *pcnt;
    if (np > PCAP) np = PCAP;
    for (int j = blockIdx.x * 256 + threadIdx.x; j < np; j += (int)gridDim.x * 256) {
        const int p  = gpairs[j];
        const int ti = p >> 9;
        const int k  = p & 511;
        const float4* zr = (const float4*)(Zc + (size_t)ti * 256);
        const float4* wr = (const float4*)(W + (size_t)k * DD);
        float a8 = 0.f;
        #pragma unroll 4
        for (int q = 0; q < 64; ++q) {
            float4 w4 = wr[q];
            float4 z4 = zr[q];
            a8 = fmaf(z4.x, w4.x, a8);
            a8 = fmaf(z4.y, w4.y, a8);
            a8 = fmaf(z4.z, w4.z, a8);
            a8 = fmaf(z4.w, w4.w, a8);
        }
        float da = __fadd_rn(__fsub_rn(zq[ti], __fmul_rn(2.0f, a8)), wsq[k]);
        unsigned long long key =
            ((unsigned long long)__float_as_uint(da) << 32) | (unsigned int)k;
        atomicMin(&slots[ti], key);
    }
}

// ---------------------------------------------------------------------------
// Final readout (skipped on overflow): out[bt] = winning k from slots.
// ---------------------------------------------------------------------------
__global__ __launch_bounds__(256) void vq_final(const int* __restrict__ gties,
                                                const int* __restrict__ gcnt,
                                                const int* __restrict__ oflow,
                                                const unsigned long long* __restrict__ slots,
                                                int* __restrict__ out) {
    if (*oflow) return;
    const int n = *gcnt;
    for (int j = blockIdx.x * 256 + threadIdx.x; j < n; j += (int)gridDim.x * 256) {
        out[gties[j]] = (int)(slots[j] & 511ULL);
    }
}

// ---------------------------------------------------------------------------
// Full tie fix (R2-validated). Big tier: runs only on overflow (oflow!=0).
// Tier-2: oflow == nullptr -> always runs.
// ---------------------------------------------------------------------------
__global__ __launch_bounds__(256) void vq_fix(const float* __restrict__ Z,
                                              const float* __restrict__ W,
                                              const float* __restrict__ wsq,
                                              const int* __restrict__ gties,
                                              const int* __restrict__ gcnt,
                                              int* __restrict__ out,
                                              const int* __restrict__ oflow) {
    if (oflow != nullptr && *oflow == 0) return;

    __shared__ __align__(16) float Zs[8][256];
    __shared__ double pz[8][32];
    __shared__ float  zsqs[8];
    __shared__ int    bts[8];
    __shared__ float  rv[8][4];
    __shared__ int    ri[8][4];

    const int tid  = threadIdx.x;
    const int lane = tid & 63;
    const int wvx  = tid >> 6;
    const int n    = *gcnt;

    for (int base = blockIdx.x * 8; base < n; base += (int)gridDim.x * 8) {
        const int m = (n - base < 8) ? (n - base) : 8;
        __syncthreads();
        if (tid < 8) bts[tid] = gties[base + ((tid < m) ? tid : 0)];
        __syncthreads();

        #pragma unroll
        for (int i = 0; i < 8; ++i) {
            if (i < m) {
                int tb = bts[i];
                int bb = tb >> 12, t = tb & 4095;
                Zs[i][tid] = Z[(size_t)bb * DD * NT + (size_t)tid * NT + t];
            }
        }
        __syncthreads();

        {
            int i = tid >> 5, seg = tid & 31;
            double s = 0.0;
            #pragma unroll
            for (int j = 0; j < 8; ++j) {
                double zz = (double)Zs[i][seg * 8 + j];
                s = fma(zz, zz, s);
            }
            pz[i][seg] = s;
        }
        __syncthreads();
        if (tid < 8) {
            double s = 0.0;
            #pragma unroll
            for (int j = 0; j < 32; ++j) s += pz[tid][j];
            zsqs[tid] = (float)s;
        }
        __syncthreads();

        float da[2][8];
        #pragma unroll
        for (int rr = 0; rr < 2; ++rr) {
            int k = tid + rr * 256;
            const float4* wr = (const float4*)(W + (size_t)k * DD);
            float a8[8];
            #pragma unroll
            for (int i = 0; i < 8; ++i) a8[i] = 0.f;
            #pragma unroll 2
            for (int q = 0; q < 64; ++q) {
                float4 w4 = wr[q];
                #pragma unroll
                for (int i = 0; i < 8; ++i) {
                    float4 z4 = *(const float4*)&Zs[i][4 * q];   // LDS broadcast
                    a8[i] = fmaf(z4.x, w4.x, a8[i]);
                    a8[i] = fmaf(z4.y, w4.y, a8[i]);
                    a8[i] = fmaf(z4.z, w4.z, a8[i]);
                    a8[i] = fmaf(z4.w, w4.w, a8[i]);
                }
            }
            float wqv = wsq[k];
            #pragma unroll
            for (int i = 0; i < 8; ++i)
                da[rr][i] = __fadd_rn(__fsub_rn(zsqs[i], __fmul_rn(2.0f, a8[i])), wqv);
        }

        #pragma unroll
        for (int i = 0; i < 8; ++i) {
            float v = da[0][i]; int ix = tid;
            if (da[1][i] < v) { v = da[1][i]; ix = tid + 256; }
            #pragma unroll
            for (int mk = 1; mk <= 32; mk <<= 1) {
                float ov = __shfl_xor(v, mk);
                int   oi = __shfl_xor(ix, mk);
                if (ov < v || (ov == v && oi < ix)) { v = ov; ix = oi; }
            }
            if (lane == 0) { rv[i][wvx] = v; ri[i][wvx] = ix; }
        }
        __syncthreads();
        if (tid < 8 && tid < m) {
            float v = INFINITY; int ix = 0x7fffffff;
            #pragma unroll
            for (int w = 0; w < 4; ++w) {
                if (rv[tid][w] < v || (rv[tid][w] == v && ri[tid][w] < ix)) {
                    v = rv[tid][w]; ix = ri[tid][w];
                }
            }
            out[bts[tid]] = ix;
        }
    }
}

// ---------------------------------------------------------------------------
// Phase 1 (tier-2, R2-validated): 4-wave, in-kernel staging.
// ---------------------------------------------------------------------------
__global__ __launch_bounds__(256, 2) void vq_phase1_reg(const float* __restrict__ Z,
                                                        const unsigned short* __restrict__ Wpp,
                                                        const float* __restrict__ wsq,
                                                        int* __restrict__ out,
                                                        int* __restrict__ gties,
                                                        int* __restrict__ gcnt) {
    __shared__ __align__(16) short As[64 * ASTR];
    __shared__ int lcnt, gbase;

    const int tid  = threadIdx.x;
    const int wave = tid >> 6;
    const int lane = tid & 63;
    const int lm   = lane & 15;
    const int lq   = lane >> 4;
    const int nw   = wave;

    const int bx = blockIdx.x;
    const int b  = bx >> 6;
    const int t0 = (bx & 63) * 64;

    const int t_l = tid & 63;
    const int dgs = tid >> 6;

    const float* zcol = Z + (size_t)b * DD * NT + t0 + t_l;

    if (tid == 0) lcnt = 0;

    double zacc = 0.0;
    #pragma unroll
    for (int half = 0; half < 2; ++half) {
        float zv[32];
        #pragma unroll
        for (int j = 0; j < 32; ++j)
            zv[j] = zcol[(size_t)(dgs * 64 + half * 32 + j) * NT];
        #pragma unroll
        for (int j = 0; j < 32; ++j)
            zacc = fma((double)zv[j], (double)zv[j], zacc);
        #pragma unroll
        for (int j0 = 0; j0 < 32; j0 += 4) {
            __align__(16) unsigned int u[4];
            #pragma unroll
            for (int q = 0; q < 4; ++q) {
                float z = zv[j0 + q];
                _Float16 zh = (_Float16)z;
                float rz = z - (float)zh;
                unsigned short hs, ls;
                __builtin_memcpy(&hs, &zh, 2);
                ls = f16bits(rz);
                u[q] = (unsigned int)hs | ((unsigned int)ls << 16);
            }
            *(int4*)&As[t_l * ASTR + (dgs * 64 + half * 32 + j0) * 2] = *(const int4*)u;
        }
    }
    __syncthreads();

    const unsigned short* wb = Wpp + ((size_t)(nw * 128 + lm) * 32) + lq * 8;

    f32x4 acc[4][8];
    #pragma unroll
    for (int mt = 0; mt < 4; ++mt)
        #pragma unroll
        for (int nt = 0; nt < 8; ++nt)
            acc[mt][nt] = (f32x4){0.f, 0.f, 0.f, 0.f};

    int4 bv0[8], bv1[8];
    #pragma unroll
    for (int nt = 0; nt < 8; ++nt)
        bv0[nt] = *(const int4*)(wb + nt * 512);

    #pragma unroll
    for (int c = 0; c < NCH; ++c) {
        int4* cur = (c & 1) ? bv1 : bv0;
        int4* nxt = (c & 1) ? bv0 : bv1;
        if (c < NCH - 1) {
            const unsigned short* wp = wb + (size_t)(c + 1) * 16384;
            #pragma unroll
            for (int nt = 0; nt < 8; ++nt)
                nxt[nt] = *(const int4*)(wp + nt * 512);
        }
        f16x8 a[4];
        #pragma unroll
        for (int mt = 0; mt < 4; ++mt)
            a[mt] = *(const f16x8*)&As[(mt * 16 + lm) * ASTR + c * 32 + lq * 8];
        #pragma unroll
        for (int mt = 0; mt < 4; ++mt)
            #pragma unroll
            for (int nt = 0; nt < 8; ++nt)
                acc[mt][nt] = __builtin_amdgcn_mfma_f32_16x16x32_f16(
                    a[mt], *(const f16x8*)&cur[nt], acc[mt][nt], 0, 0, 0);
    }

    __syncthreads();
    double* zred = (double*)As;
    float*  zf   = (float*)(As + 1024);
    float*  cb1  = (float*)(As + 1536);
    float*  cb2  = (float*)(As + 2048);
    int*    cbi  = (int*)(As + 2560);
    int*    llist = (int*)(As + 3072);

    zred[dgs * 64 + t_l] = zacc;
    __syncthreads();
    if (tid < 64) {
        double s = zred[tid];
        #pragma unroll
        for (int p = 1; p < 4; ++p) s += zred[p * 64 + tid];
        zf[tid] = (float)s;
    }
    __syncthreads();

    float wq[8];
    #pragma unroll
    for (int nt = 0; nt < 8; ++nt)
        wq[nt] = wsq[nw * 128 + nt * 16 + lm];
    const int kbase = nw * 128 + lm;

    #pragma unroll
    for (int mt = 0; mt < 4; ++mt) {
        #pragma unroll
        for (int r = 0; r < 4; ++r) {
            float zz = zf[mt * 16 + lq * 4 + r];
            float q1 = INFINITY, q2 = INFINITY;
            int i1 = 0x7fffffff;
            #pragma unroll
            for (int nt = 0; nt < 8; ++nt) {
                float c2   = __fmul_rn(acc[mt][nt][r], 4.8828125e-4f);
                float dist = __fadd_rn(__fsub_rn(zz, c2), wq[nt]);
                int kk = kbase + nt * 16;
                if (dist < q1 || (dist == q1 && kk < i1)) { q2 = q1; q1 = dist; i1 = kk; }
                else if (dist < q2) q2 = dist;
            }
            #pragma unroll
            for (int mk = 1; mk <= 8; mk <<= 1) {
                float o1 = __shfl_xor(q1, mk);
                float o2 = __shfl_xor(q2, mk);
                int   oi = __shfl_xor(i1, mk);
                if (o1 < q1 || (o1 == q1 && oi < i1)) { q2 = fminf(q1, o2); q1 = o1; i1 = oi; }
                else { q2 = fminf(o1, q2); }
            }
            if (lm == 0) {
                int m = mt * 16 + lq * 4 + r;
                cb1[m * 4 + nw] = q1;
                cb2[m * 4 + nw] = q2;
                cbi[m * 4 + nw] = i1;
            }
        }
    }
    __syncthreads();
    if (tid < 64) {
        float q1 = cb1[tid * 4], q2 = cb2[tid * 4];
        int   i1 = cbi[tid * 4];
        #pragma unroll
        for (int p = 1; p < 4; ++p) {
            float c1 = cb1[tid * 4 + p], c2v = cb2[tid * 4 + p];
            int   ci = cbi[tid * 4 + p];
            if (c1 < q1 || (c1 == q1 && ci < i1)) { q2 = fminf(q1, c2v); q1 = c1; i1 = ci; }
            else { q2 = fminf(q2, c1); }
        }
        out[(size_t)b * NT + t0 + tid] = i1;
        if (q2 - q1 <= MARGIN) {
            int p = atomicAdd(&lcnt, 1);
            llist[p] = b * NT + t0 + tid;
        }
    }
    __syncthreads();
    if (tid == 0) gbase = (lcnt > 0) ? atomicAdd(gcnt, lcnt) : 0;
    __syncthreads();
    if (tid < lcnt) gties[gbase + tid] = llist[tid];
}

// ---------------------------------------------------------------------------
// Fallback (R1 kernel) if ws is too small.
// ---------------------------------------------------------------------------
#define BT 128
#define BK 128
#define DCHUNK 32
#define NKC (NK / BK)
#define NDC (DD / DCHUNK)
#define WSTR (BK + 4)

__global__ __launch_bounds__(256) void vq_fallback(const float* __restrict__ Z,
                                                   const float* __restrict__ W,
                                                   int* __restrict__ out) {
    __shared__ __align__(16) float Zs[DCHUNK * BT];
    __shared__ __align__(16) float Ws[DCHUNK * WSTR];
    __shared__ float wsqs[NK];

    const int tid = threadIdx.x;
    const int tx  = tid & 15;
    const int ty  = tid >> 4;
    const int b   = blockIdx.y;
    const int t0  = blockIdx.x * BT;

    for (int k = tid; k < NK; k += 256) {
        const float4* row = (const float4*)(W + (size_t)k * DD);
        double s = 0.0;
        for (int i = 0; i < DD / 4; ++i) {
            float4 v = row[i];
            s += (double)v.x * v.x + (double)v.y * v.y + (double)v.z * v.z + (double)v.w * v.w;
        }
        wsqs[k] = (float)s;
    }

    const float* Zb = Z + (size_t)b * DD * NT + t0;

    float best[8]; int bidx[8];
    #pragma unroll
    for (int a = 0; a < 8; ++a) { best[a] = INFINITY; bidx[a] = 0x7fffffff; }
    double zsqd[8];
    #pragma unroll
    for (int a = 0; a < 8; ++a) zsqd[a] = 0.0;
    float zsqf[8];

    for (int kc = 0; kc < NKC; ++kc) {
        float acc[8][8];
        #pragma unroll
        for (int a = 0; a < 8; ++a)
            #pragma unroll
            for (int c = 0; c < 8; ++c) acc[a][c] = 0.f;

        for (int dc = 0; dc < NDC; ++dc) {
            const int d0 = dc * DCHUNK;
            __syncthreads();
            #pragma unroll
            for (int i = 0; i < 4; ++i) {
                int f  = tid + i * 256;
                int r  = f >> 5;
                int c4 = f & 31;
                float4 v = *(const float4*)(Zb + (size_t)(d0 + r) * NT + c4 * 4);
                *(float4*)(&Zs[r * BT + c4 * 4]) = v;
            }
            #pragma unroll
            for (int i = 0; i < 4; ++i) {
                int u  = tid + i * 256;
                int k  = u >> 3;
                int rg = u & 7;
                float4 v = *(const float4*)(W + (size_t)(kc * BK + k) * DD + d0 + rg * 4);
                Ws[(rg * 4 + 0) * WSTR + k] = v.x;
                Ws[(rg * 4 + 1) * WSTR + k] = v.y;
                Ws[(rg * 4 + 2) * WSTR + k] = v.z;
                Ws[(rg * 4 + 3) * WSTR + k] = v.w;
            }
            __syncthreads();
            #pragma unroll 4
            for (int d = 0; d < DCHUNK; ++d) {
                float4 z0 = *(const float4*)(&Zs[d * BT + ty * 8]);
                float4 z1 = *(const float4*)(&Zs[d * BT + ty * 8 + 4]);
                float4 w0 = *(const float4*)(&Ws[d * WSTR + tx * 8]);
                float4 w1 = *(const float4*)(&Ws[d * WSTR + tx * 8 + 4]);
                float za[8] = {z0.x, z0.y, z0.z, z0.w, z1.x, z1.y, z1.z, z1.w};
                float wa[8] = {w0.x, w0.y, w0.z, w0.w, w1.x, w1.y, w1.z, w1.w};
                if (kc == 0) {
                    #pragma unroll
                    for (int a = 0; a < 8; ++a)
                        zsqd[a] = fma((double)za[a], (double)za[a], zsqd[a]);
                }
                #pragma unroll
                for (int a = 0; a < 8; ++a)
                    #pragma unroll
                    for (int c = 0; c < 8; ++c)
                        acc[a][c] = fmaf(za[a], wa[c], acc[a][c]);
            }
        }
        if (kc == 0) {
            #pragma unroll
            for (int a = 0; a < 8; ++a) zsqf[a] = (float)zsqd[a];
        }
        #pragma unroll
        for (int c = 0; c < 8; ++c) {
            int   kg = kc * BK + tx * 8 + c;
            float wqv = wsqs[kg];
            #pragma unroll
            for (int a = 0; a < 8; ++a) {
                float c2   = __fmul_rn(2.0f, acc[a][c]);
                float s    = __fsub_rn(zsqf[a], c2);
                float dist = __fadd_rn(s, wqv);
                if (dist < best[a] || (dist == best[a] && kg < bidx[a])) {
                    best[a] = dist; bidx[a] = kg;
                }
            }
        }
    }
    __syncthreads();
    float* redv = Zs;
    int*   redi = (int*)Ws;
    #pragma unroll
    for (int a = 0; a < 8; ++a) {
        int tl2 = ty * 8 + a;
        redv[tl2 * 16 + tx] = best[a];
        redi[tl2 * 16 + tx] = bidx[a];
    }
    __syncthreads();
    if (tid < BT) {
        float bv = INFINITY; int bi = 0x7fffffff;
        #pragma unroll
        for (int j = 0; j < 16; ++j) {
            float v = redv[tid * 16 + j];
            int   i = redi[tid * 16 + j];
            if (v < bv || (v == bv && i < bi)) { bv = v; bi = i; }
        }
        out[(size_t)b * NT + t0 + tid] = bi;
    }
}

extern "C" void kernel_launch(void* const* d_in, const int* in_sizes, int n_in,
                              void* d_out, int out_size, void* d_ws, size_t ws_size,
                              hipStream_t stream) {
    const float* Z = (const float*)d_in[0];   // [B, D, T]
    const float* W = (const float*)d_in[1];   // [K, D]
    int* out = (int*)d_out;                   // [B, T]

    // ---- tier-big layout
    const size_t OFF_WSQ  = 0;                         // 512 f32
    const size_t OFF_CNT  = 2048;                      // gcnt
    const size_t OFF_PCNT = 2052;                      // pcnt
    const size_t OFF_OFL  = 2056;                      // oflow
    const size_t OFF_ZQ   = 4096;                      // 131072 f32 (512 KB)
    const size_t OFF_WPP  = OFF_ZQ + 524288;           // 512 KB
    const size_t OFF_TIE  = OFF_WPP + 524288;          // 131072 ints
    const size_t OFF_SLOT = OFF_TIE + 524288;          // 131072 u64 (1 MB)
    const size_t OFF_PAIR = OFF_SLOT + 1048576;        // PCAP ints (2 MB)
    const size_t OFF_ZC   = OFF_PAIR + (size_t)PCAP * 4;          // ZCROWS KB
    const size_t NEED_BIG = OFF_ZC + (size_t)ZCROWS * 1024;       // ~69.6 MB

    // ---- tier-2 layout (R2 path)
    const size_t T2_WSQ = 0;
    const size_t T2_CNT = 2048;
    const size_t T2_WPP = 4096;
    const size_t T2_TIE = T2_WPP + 524288;
    const size_t NEED_T2 = T2_TIE + 524288;

    if (ws_size >= NEED_BIG) {
        float* wsq  = (float*)((char*)d_ws + OFF_WSQ);
        int*   gcnt = (int*)((char*)d_ws + OFF_CNT);
        int*   pcnt = (int*)((char*)d_ws + OFF_PCNT);
        int*   ofl  = (int*)((char*)d_ws + OFF_OFL);
        float* zq   = (float*)((char*)d_ws + OFF_ZQ);
        unsigned short* wpp = (unsigned short*)((char*)d_ws + OFF_WPP);
        int*   gties = (int*)((char*)d_ws + OFF_TIE);
        unsigned long long* slots = (unsigned long long*)((char*)d_ws + OFF_SLOT);
        int*   gpairs = (int*)((char*)d_ws + OFF_PAIR);
        float* zc   = (float*)((char*)d_ws + OFF_ZC);

        prep_kernel<<<dim3(NCH + 1), dim3(512), 0, stream>>>(W, wpp, wsq, gcnt, pcnt, ofl);
        vq_phase1<<<dim3(2048), dim3(512), 0, stream>>>(Z, wpp, wsq, out, gties, gcnt,
                                                        zc, zq, slots, gpairs, pcnt, ofl);
        vq_fix_pairs<<<dim3(512), dim3(256), 0, stream>>>(W, wsq, zc, zq, gpairs, pcnt, slots);
        vq_fix<<<dim3(256), dim3(256), 0, stream>>>(Z, W, wsq, gties, gcnt, out, ofl);
        vq_final<<<dim3(256), dim3(256), 0, stream>>>(gties, gcnt, ofl, slots, out);
    } else if (ws_size >= NEED_T2) {
        float* wsq  = (float*)((char*)d_ws + T2_WSQ);
        int*   gcnt = (int*)((char*)d_ws + T2_CNT);
        unsigned short* wpp = (unsigned short*)((char*)d_ws + T2_WPP);
        int*   gties = (int*)((char*)d_ws + T2_TIE);

        prep_kernel<<<dim3(NCH + 1), dim3(512), 0, stream>>>(W, wpp, wsq, gcnt, gcnt, gcnt);
        vq_phase1_reg<<<dim3(2048), dim3(256), 0, stream>>>(Z, wpp, wsq, out, gties, gcnt);
        vq_fix<<<dim3(256), dim3(256), 0, stream>>>(Z, W, wsq, gties, gcnt, out, nullptr);
    } else {
        vq_fallback<<<dim3(NT / BT, NB), dim3(256), 0, stream>>>(Z, W, out);
    }
}